// Round 7
// baseline (160.137 us; speedup 1.0000x reference)
//
#include <hip/hip_runtime.h>
#include <hip/hip_bf16.h>

namespace {

constexpr int S = 2048;
constexpr int D = 64;
constexpr int BH = 24;        // 2 batches * 12 heads
constexpr int QT = 64;        // q rows per block
constexpr int KT = 64;        // keys per tile
constexpr int NKT = S / KT;   // 32
constexpr int PAD = 72;       // LDS row stride in ushorts (16B-aligned rows; R2 lesson)

typedef __attribute__((ext_vector_type(8))) __bf16 bf16x8;
typedef __attribute__((ext_vector_type(4))) __bf16 bf16x4;
typedef __attribute__((ext_vector_type(4))) float  f32x4;
typedef __attribute__((ext_vector_type(4))) unsigned short u16x4;

// f32x4 -> bf16x4 via native v_cvt_pk_bf16_f32 (RNE)
__device__ inline bf16x4 cvt4(f32x4 f) {
    return __builtin_convertvector(f, bf16x4);
}

// ---------------- prologue kernels (bf16 staging into d_ws; R5-validated) ----------------

__global__ __launch_bounds__(256)
void cast_bf16_kernel(const float* __restrict__ src, unsigned short* __restrict__ dst, int n4) {
    int i = blockIdx.x * 256 + threadIdx.x;
    const int stride = gridDim.x * 256;
    for (; i < n4; i += stride) {
        f32x4 f = *reinterpret_cast<const f32x4*>(src + 4 * (size_t)i);
        *reinterpret_cast<bf16x4*>(dst + 4 * (size_t)i) = cvt4(f);
    }
}

// V [bh][s][d] f32 -> Vt [bh][d][s] bf16 (64x64 LDS tile transpose)
__global__ __launch_bounds__(256)
void transpose_v_kernel(const float* __restrict__ v, unsigned short* __restrict__ vt) {
    __shared__ unsigned short Ls[64][PAD];
    const int bh = blockIdx.y;
    const int s0 = blockIdx.x * 64;
    const int tid = threadIdx.x;
    #pragma unroll
    for (int ii = 0; ii < 4; ++ii) {
        int idx = tid + ii * 256;
        int sr = idx >> 4, dc = (idx & 15) * 4;
        f32x4 f = *reinterpret_cast<const f32x4*>(v + ((size_t)bh * S + s0 + sr) * D + dc);
        *reinterpret_cast<bf16x4*>(&Ls[sr][dc]) = cvt4(f);
    }
    __syncthreads();
    #pragma unroll
    for (int ii = 0; ii < 4; ++ii) {
        int idx = tid + ii * 256;
        int dr = idx >> 4, sc = (idx & 15) * 4;
        u16x4 w = { Ls[sc + 0][dr], Ls[sc + 1][dr], Ls[sc + 2][dr], Ls[sc + 3][dr] };
        *reinterpret_cast<u16x4*>(vt + ((size_t)bh * D + dr) * S + s0 + sc) = w;
    }
}

// ---------------- main monolith: R4 skeleton, bf16 staging, XCD swizzle ----------------

__global__ __launch_bounds__(256, 3)
void sdpa_main(const float* __restrict__ q,
               const unsigned short* __restrict__ Kb,
               const unsigned short* __restrict__ Vtb,
               float* __restrict__ out, float* __restrict__ attn) {
    __shared__ unsigned short Ks[2][KT][PAD];
    __shared__ unsigned short Vt[2][D][PAD];   // Vt[d][key within tile]
    __shared__ unsigned short QPs[QT][PAD];    // Q staging, then P (rows wave-private)

    const int tid  = threadIdx.x;
    const int wid  = tid >> 6;
    const int lane = tid & 63;
    const int g    = lane >> 4;
    const int r16  = lane & 15;

    // XCD swizzle: 768 blocks, 96 contiguous logical tiles (=3 full bh) per XCD
    const int logical = (blockIdx.x & 7) * 96 + (blockIdx.x >> 3);
    const int bh = logical >> 5;
    const int q0 = (logical & 31) * QT;

    const float*          qg  = q   + ((size_t)bh * S + q0) * D;
    const unsigned short* kg  = Kb  + (size_t)bh * S * D;
    const unsigned short* vtg = Vtb + (size_t)bh * D * S;
    float* attng = attn + ((size_t)bh * S + q0) * S;
    float* outg  = out  + ((size_t)bh * S + q0) * D;

    // ---- stage Q tile (fp32 -> bf16, once) ----
    #pragma unroll
    for (int ii = 0; ii < 4; ++ii) {
        int idx = tid + ii * 256;
        int r = idx >> 4, c = (idx & 15) * 4;
        f32x4 f = *reinterpret_cast<const f32x4*>(qg + r * D + c);
        *reinterpret_cast<bf16x4*>(&QPs[r][c]) = cvt4(f);
    }
    __syncthreads();
    const bf16x8 bQ0 = *(const bf16x8*)&QPs[wid * 16 + r16][g * 8];
    const bf16x8 bQ1 = *(const bf16x8*)&QPs[wid * 16 + r16][32 + g * 8];

    // staging coords: thread -> (row, 16-short column group); 32B per load
    const int kr = tid >> 2;            // 0..63 (K row / V d-row)
    const int kc = (tid & 3) * 16;      // 0,16,32,48 shorts

    // ================= phase 1: row sums of exp(scores/64) =================
    float rs0 = 0.f, rs1 = 0.f;
    bf16x8 pk0, pk1, pv0, pv1;

    {   // prologue: tile 0
        const unsigned short* p = kg + (size_t)kr * D + kc;
        pk0 = *(const bf16x8*)p;
        pk1 = *(const bf16x8*)(p + 8);
        *(bf16x8*)&Ks[0][kr][kc]     = pk0;
        *(bf16x8*)&Ks[0][kr][kc + 8] = pk1;
    }
    __syncthreads();

    for (int t = 0; t < NKT; ++t) {
        const int cur = t & 1;
        if (t + 1 < NKT) {
            const unsigned short* p = kg + (size_t)((t + 1) * KT + kr) * D + kc;
            pk0 = *(const bf16x8*)p;
            pk1 = *(const bf16x8*)(p + 8);
        }
        #pragma unroll
        for (int cf = 0; cf < 4; ++cf) {
            bf16x8 aK0 = *(const bf16x8*)&Ks[cur][cf * 16 + r16][g * 8];
            bf16x8 aK1 = *(const bf16x8*)&Ks[cur][cf * 16 + r16][32 + g * 8];
            f32x4 acc = {0.f, 0.f, 0.f, 0.f};
            acc = __builtin_amdgcn_mfma_f32_16x16x32_bf16(aK0, bQ0, acc, 0, 0, 0);
            acc = __builtin_amdgcn_mfma_f32_16x16x32_bf16(aK1, bQ1, acc, 0, 0, 0);
            rs0 += __expf(acc[0] * (1.0f / 64.0f)) + __expf(acc[2] * (1.0f / 64.0f));
            rs1 += __expf(acc[1] * (1.0f / 64.0f)) + __expf(acc[3] * (1.0f / 64.0f));
        }
        if (t + 1 < NKT) {
            const int nxt = (t + 1) & 1;
            *(bf16x8*)&Ks[nxt][kr][kc]     = pk0;
            *(bf16x8*)&Ks[nxt][kr][kc + 8] = pk1;
            __syncthreads();
        }
    }
    float rs = rs0 + rs1;
    rs += __shfl_xor(rs, 16, 64);
    rs += __shfl_xor(rs, 32, 64);
    const float inv = 1.0f / rs;

    // ====== phase 2: recompute scores, write attn (nt float4), accumulate PV ======
    f32x4 oacc[4];
    #pragma unroll
    for (int n = 0; n < 4; ++n) oacc[n] = {0.f, 0.f, 0.f, 0.f};

    {   // prologue: tile 0 (K + V)
        const unsigned short* p  = kg  + (size_t)kr * D + kc;
        const unsigned short* pv = vtg + (size_t)kr * S + kc;
        pk0 = *(const bf16x8*)p;   pk1 = *(const bf16x8*)(p + 8);
        pv0 = *(const bf16x8*)pv;  pv1 = *(const bf16x8*)(pv + 8);
        *(bf16x8*)&Ks[0][kr][kc]     = pk0;
        *(bf16x8*)&Ks[0][kr][kc + 8] = pk1;
        *(bf16x8*)&Vt[0][kr][kc]     = pv0;
        *(bf16x8*)&Vt[0][kr][kc + 8] = pv1;
    }
    __syncthreads();

    for (int t = 0; t < NKT; ++t) {
        const int cur = t & 1;
        if (t + 1 < NKT) {
            const unsigned short* p  = kg  + (size_t)((t + 1) * KT + kr) * D + kc;
            const unsigned short* pv = vtg + (size_t)kr * S + (t + 1) * KT + kc;
            pk0 = *(const bf16x8*)p;   pk1 = *(const bf16x8*)(p + 8);
            pv0 = *(const bf16x8*)pv;  pv1 = *(const bf16x8*)(pv + 8);
        }
        #pragma unroll
        for (int cf = 0; cf < 4; ++cf) {
            bf16x8 aK0 = *(const bf16x8*)&Ks[cur][cf * 16 + r16][g * 8];
            bf16x8 aK1 = *(const bf16x8*)&Ks[cur][cf * 16 + r16][32 + g * 8];
            f32x4 acc = {0.f, 0.f, 0.f, 0.f};
            acc = __builtin_amdgcn_mfma_f32_16x16x32_bf16(aK0, bQ0, acc, 0, 0, 0);
            acc = __builtin_amdgcn_mfma_f32_16x16x32_bf16(aK1, bQ1, acc, 0, 0, 0);
            f32x4 pst;
            #pragma unroll
            for (int e = 0; e < 4; ++e)
                pst[e] = __expf(acc[e] * (1.0f / 64.0f)) * inv;
            __builtin_nontemporal_store(pst, reinterpret_cast<f32x4*>(
                attng + (size_t)(wid * 16 + r16) * S + t * KT + cf * 16 + g * 4));
            *reinterpret_cast<bf16x4*>(&QPs[wid * 16 + r16][cf * 16 + g * 4]) = cvt4(pst);
        }
        bf16x8 aP0 = *(const bf16x8*)&QPs[wid * 16 + r16][g * 8];
        bf16x8 aP1 = *(const bf16x8*)&QPs[wid * 16 + r16][32 + g * 8];
        #pragma unroll
        for (int n = 0; n < 4; ++n) {
            bf16x8 bv0 = *(const bf16x8*)&Vt[cur][n * 16 + r16][g * 8];
            bf16x8 bv1 = *(const bf16x8*)&Vt[cur][n * 16 + r16][32 + g * 8];
            oacc[n] = __builtin_amdgcn_mfma_f32_16x16x32_bf16(aP0, bv0, oacc[n], 0, 0, 0);
            oacc[n] = __builtin_amdgcn_mfma_f32_16x16x32_bf16(aP1, bv1, oacc[n], 0, 0, 0);
        }
        if (t + 1 < NKT) {
            const int nxt = (t + 1) & 1;
            *(bf16x8*)&Ks[nxt][kr][kc]     = pk0;
            *(bf16x8*)&Ks[nxt][kr][kc + 8] = pk1;
            *(bf16x8*)&Vt[nxt][kr][kc]     = pv0;
            *(bf16x8*)&Vt[nxt][kr][kc + 8] = pv1;
            __syncthreads();
        }
    }

    // ---- epilogue ----
    #pragma unroll
    for (int n = 0; n < 4; ++n) {
        #pragma unroll
        for (int e = 0; e < 4; ++e) {
            __builtin_nontemporal_store(oacc[n][e],
                outg + (size_t)(wid * 16 + g * 4 + e) * D + n * 16 + r16);
        }
    }
}

// ---------------- fallback (proven R4 monolith) if ws too small ----------------
__global__ __launch_bounds__(256, 3)
void sdpa_fallback(const float* __restrict__ q,
                   const float* __restrict__ k,
                   const float* __restrict__ v,
                   float* __restrict__ out,
                   float* __restrict__ attn) {
    __shared__ unsigned short Ks[2][KT][PAD];
    __shared__ unsigned short Vt[2][D][PAD];
    __shared__ unsigned short QPs[QT][PAD];

    const int tid  = threadIdx.x;
    const int wid  = tid >> 6;
    const int lane = tid & 63;
    const int g    = lane >> 4;
    const int r16  = lane & 15;
    const int bh   = blockIdx.y;
    const int q0   = blockIdx.x * QT;

    const float* qg = q + ((size_t)bh * S + q0) * D;
    const float* kg = k + (size_t)bh * S * D;
    const float* vg = v + (size_t)bh * S * D;
    float* attng = attn + ((size_t)bh * S + q0) * S;
    float* outg  = out  + ((size_t)bh * S + q0) * D;

    #pragma unroll
    for (int ii = 0; ii < 4; ++ii) {
        int idx = tid + ii * 256;
        int r = idx >> 4, c = (idx & 15) * 4;
        f32x4 f = *reinterpret_cast<const f32x4*>(qg + r * D + c);
        *reinterpret_cast<bf16x4*>(&QPs[r][c]) = cvt4(f);
    }
    __syncthreads();
    const bf16x8 bQ0 = *(const bf16x8*)&QPs[wid * 16 + r16][g * 8];
    const bf16x8 bQ1 = *(const bf16x8*)&QPs[wid * 16 + r16][32 + g * 8];

    float rs = 0.0f;
    f32x4 pK[4];

    #pragma unroll
    for (int ii = 0; ii < 4; ++ii) {
        int idx = tid + ii * 256;
        int r = idx >> 4, c = (idx & 15) * 4;
        pK[ii] = *reinterpret_cast<const f32x4*>(kg + r * D + c);
    }
    #pragma unroll
    for (int ii = 0; ii < 4; ++ii) {
        int idx = tid + ii * 256;
        int r = idx >> 4, c = (idx & 15) * 4;
        *reinterpret_cast<bf16x4*>(&Ks[0][r][c]) = cvt4(pK[ii]);
    }
    __syncthreads();

    for (int t = 0; t < NKT; ++t) {
        const int cur = t & 1;
        if (t + 1 < NKT) {
            const float* ktg = kg + (size_t)(t + 1) * KT * D;
            #pragma unroll
            for (int ii = 0; ii < 4; ++ii) {
                int idx = tid + ii * 256;
                int r = idx >> 4, c = (idx & 15) * 4;
                pK[ii] = *reinterpret_cast<const f32x4*>(ktg + r * D + c);
            }
        }
        #pragma unroll
        for (int cf = 0; cf < 4; ++cf) {
            bf16x8 aK0 = *(const bf16x8*)&Ks[cur][cf * 16 + r16][g * 8];
            bf16x8 aK1 = *(const bf16x8*)&Ks[cur][cf * 16 + r16][32 + g * 8];
            f32x4 acc = {0.f, 0.f, 0.f, 0.f};
            acc = __builtin_amdgcn_mfma_f32_16x16x32_bf16(aK0, bQ0, acc, 0, 0, 0);
            acc = __builtin_amdgcn_mfma_f32_16x16x32_bf16(aK1, bQ1, acc, 0, 0, 0);
            #pragma unroll
            for (int e = 0; e < 4; ++e)
                rs += __expf(acc[e] * (1.0f / 64.0f));
        }
        if (t + 1 < NKT) {
            const int nxt = (t + 1) & 1;
            #pragma unroll
            for (int ii = 0; ii < 4; ++ii) {
                int idx = tid + ii * 256;
                int r = idx >> 4, c = (idx & 15) * 4;
                *reinterpret_cast<bf16x4*>(&Ks[nxt][r][c]) = cvt4(pK[ii]);
            }
            __syncthreads();
        }
    }
    rs += __shfl_xor(rs, 16, 64);
    rs += __shfl_xor(rs, 32, 64);
    const float inv = 1.0f / rs;

    f32x4 oacc[4];
    #pragma unroll
    for (int n = 0; n < 4; ++n) oacc[n] = {0.f, 0.f, 0.f, 0.f};

    f32x4 pV[4];
    const int vk0 = (tid & 15) * 4;
    const int vc  = (tid >> 4) * 4;

    #pragma unroll
    for (int ii = 0; ii < 4; ++ii) {
        int idx = tid + ii * 256;
        int r = idx >> 4, c = (idx & 15) * 4;
        pK[ii] = *reinterpret_cast<const f32x4*>(kg + r * D + c);
        pV[ii] = *reinterpret_cast<const f32x4*>(vg + (vk0 + ii) * D + vc);
    }
    #pragma unroll
    for (int ii = 0; ii < 4; ++ii) {
        int idx = tid + ii * 256;
        int r = idx >> 4, c = (idx & 15) * 4;
        *reinterpret_cast<bf16x4*>(&Ks[0][r][c]) = cvt4(pK[ii]);
    }
    #pragma unroll
    for (int j = 0; j < 4; ++j) {
        f32x4 col = { pV[0][j], pV[1][j], pV[2][j], pV[3][j] };
        *reinterpret_cast<bf16x4*>(&Vt[0][vc + j][vk0]) = cvt4(col);
    }
    __syncthreads();

    for (int t = 0; t < NKT; ++t) {
        const int cur = t & 1;
        if (t + 1 < NKT) {
            const float* ktg = kg + (size_t)(t + 1) * KT * D;
            const float* vtg = vg + (size_t)(t + 1) * KT * D;
            #pragma unroll
            for (int ii = 0; ii < 4; ++ii) {
                int idx = tid + ii * 256;
                int r = idx >> 4, c = (idx & 15) * 4;
                pK[ii] = *reinterpret_cast<const f32x4*>(ktg + r * D + c);
                pV[ii] = *reinterpret_cast<const f32x4*>(vtg + (vk0 + ii) * D + vc);
            }
        }
        #pragma unroll
        for (int cf = 0; cf < 4; ++cf) {
            bf16x8 aK0 = *(const bf16x8*)&Ks[cur][cf * 16 + r16][g * 8];
            bf16x8 aK1 = *(const bf16x8*)&Ks[cur][cf * 16 + r16][32 + g * 8];
            f32x4 acc = {0.f, 0.f, 0.f, 0.f};
            acc = __builtin_amdgcn_mfma_f32_16x16x32_bf16(aK0, bQ0, acc, 0, 0, 0);
            acc = __builtin_amdgcn_mfma_f32_16x16x32_bf16(aK1, bQ1, acc, 0, 0, 0);
            f32x4 pst;
            #pragma unroll
            for (int e = 0; e < 4; ++e)
                pst[e] = __expf(acc[e] * (1.0f / 64.0f)) * inv;
            __builtin_nontemporal_store(pst, reinterpret_cast<f32x4*>(
                attng + (size_t)(wid * 16 + r16) * S + t * KT + cf * 16 + g * 4));
            *reinterpret_cast<bf16x4*>(&QPs[wid * 16 + r16][cf * 16 + g * 4]) = cvt4(pst);
        }
        bf16x8 aP0 = *(const bf16x8*)&QPs[wid * 16 + r16][g * 8];
        bf16x8 aP1 = *(const bf16x8*)&QPs[wid * 16 + r16][32 + g * 8];
        #pragma unroll
        for (int n = 0; n < 4; ++n) {
            bf16x8 bv0 = *(const bf16x8*)&Vt[cur][n * 16 + r16][g * 8];
            bf16x8 bv1 = *(const bf16x8*)&Vt[cur][n * 16 + r16][32 + g * 8];
            oacc[n] = __builtin_amdgcn_mfma_f32_16x16x32_bf16(aP0, bv0, oacc[n], 0, 0, 0);
            oacc[n] = __builtin_amdgcn_mfma_f32_16x16x32_bf16(aP1, bv1, oacc[n], 0, 0, 0);
        }
        if (t + 1 < NKT) {
            const int nxt = (t + 1) & 1;
            #pragma unroll
            for (int ii = 0; ii < 4; ++ii) {
                int idx = tid + ii * 256;
                int r = idx >> 4, c = (idx & 15) * 4;
                *reinterpret_cast<bf16x4*>(&Ks[nxt][r][c]) = cvt4(pK[ii]);
            }
            #pragma unroll
            for (int j = 0; j < 4; ++j) {
                f32x4 col = { pV[0][j], pV[1][j], pV[2][j], pV[3][j] };
                *reinterpret_cast<bf16x4*>(&Vt[nxt][vc + j][vk0]) = cvt4(col);
            }
            __syncthreads();
        }
    }

    #pragma unroll
    for (int n = 0; n < 4; ++n) {
        #pragma unroll
        for (int e = 0; e < 4; ++e) {
            __builtin_nontemporal_store(oacc[n][e],
                outg + (size_t)(wid * 16 + g * 4 + e) * D + n * 16 + r16);
        }
    }
}

} // namespace

extern "C" void kernel_launch(void* const* d_in, const int* in_sizes, int n_in,
                              void* d_out, int out_size, void* d_ws, size_t ws_size,
                              hipStream_t stream) {
    const float* q = (const float*)d_in[0];
    const float* k = (const float*)d_in[1];
    const float* v = (const float*)d_in[2];
    float* out  = (float*)d_out;
    float* attn = out + (size_t)BH * S * D;   // outputs concatenated: (out, attn)

    constexpr size_t NEL  = (size_t)BH * S * D;   // 3,145,728 elements
    constexpr size_t NEED = NEL * 2 * 2;          // Kb + Vtb in bf16 (12.6 MB)

    if (ws_size >= NEED) {
        unsigned short* Kb  = (unsigned short*)d_ws;
        unsigned short* Vtb = Kb + NEL;
        cast_bf16_kernel<<<768, 256, 0, stream>>>(k, Kb, (int)(NEL / 4));
        transpose_v_kernel<<<dim3(S / 64, BH), 256, 0, stream>>>(v, Vtb);
        sdpa_main<<<768, 256, 0, stream>>>(q, Kb, Vtb, out, attn);
    } else {
        dim3 grid(S / QT, BH);
        sdpa_fallback<<<grid, 256, 0, stream>>>(q, k, v, out, attn);
    }
}

// Round 8
// 127.608 us; speedup vs baseline: 1.2549x; 1.2549x over previous
//
#include <hip/hip_runtime.h>
#include <hip/hip_bf16.h>

namespace {

constexpr int S = 2048;
constexpr int D = 64;
constexpr int BH = 24;        // 2 batches * 12 heads
constexpr int QT = 64;        // q rows per block
constexpr int KT = 64;        // keys per tile
constexpr int NKT = S / KT;   // 32
constexpr int PAD = 72;       // LDS row stride in ushorts (16B-aligned rows; R2 lesson)

typedef __attribute__((ext_vector_type(8))) __bf16 bf16x8;
typedef __attribute__((ext_vector_type(4))) __bf16 bf16x4;
typedef __attribute__((ext_vector_type(4))) float  f32x4;

// f32x4 -> bf16x4 via native v_cvt_pk_bf16_f32 (RNE)
__device__ inline bf16x4 cvt4(f32x4 f) {
    return __builtin_convertvector(f, bf16x4);
}

__global__ __launch_bounds__(256, 3)
void sdpa_kernel(const float* __restrict__ q,
                 const float* __restrict__ k,
                 const float* __restrict__ v,
                 float* __restrict__ out,
                 float* __restrict__ attn) {
    __shared__ unsigned short Ks[2][KT][PAD];
    __shared__ unsigned short Vt[2][D][PAD];   // Vt[d][key]
    __shared__ unsigned short QPs[QT][PAD];    // Q staging, then P (rows wave-private)

    const int tid  = threadIdx.x;
    const int wid  = tid >> 6;       // wave 0..3 owns q rows [wid*16, wid*16+16)
    const int lane = tid & 63;
    const int g    = lane >> 4;      // 16-lane group
    const int r16  = lane & 15;      // q row within wave strip (swapped layout)
    const int sr   = lane >> 3;      // store mapping: 8 rows x 8 lanes
    const int sc   = (lane & 7) * 4; // 4 contiguous elems; 8 lanes = 128B/row
    const int bh   = blockIdx.y;
    const int q0   = blockIdx.x * QT;

    const float* qg = q + ((size_t)bh * S + q0) * D;
    const float* kg = k + (size_t)bh * S * D;
    const float* vg = v + (size_t)bh * S * D;
    float* attng = attn + ((size_t)bh * S + q0) * S;
    float* outg  = out  + ((size_t)bh * S + q0) * D;

    // ---- stage Q tile (QT x D) fp32 -> bf16 LDS ----
    #pragma unroll
    for (int ii = 0; ii < 4; ++ii) {
        int idx = tid + ii * 256;
        int r = idx >> 4, c = (idx & 15) * 4;
        f32x4 f = *reinterpret_cast<const f32x4*>(qg + r * D + c);
        *reinterpret_cast<bf16x4*>(&QPs[r][c]) = cvt4(f);
    }
    __syncthreads();
    // B-frag (swapped): lane holds Q[q = r16][d = g*8 + j]
    const bf16x8 bQ0 = *(const bf16x8*)&QPs[wid * 16 + r16][g * 8];
    const bf16x8 bQ1 = *(const bf16x8*)&QPs[wid * 16 + r16][32 + g * 8];

    // ================= phase 1: row sums of exp(scores/64) =================
    float rs = 0.0f;
    f32x4 pK[4];

    #pragma unroll
    for (int ii = 0; ii < 4; ++ii) {
        int idx = tid + ii * 256;
        int r = idx >> 4, c = (idx & 15) * 4;
        pK[ii] = *reinterpret_cast<const f32x4*>(kg + r * D + c);
    }
    #pragma unroll
    for (int ii = 0; ii < 4; ++ii) {
        int idx = tid + ii * 256;
        int r = idx >> 4, c = (idx & 15) * 4;
        *reinterpret_cast<bf16x4*>(&Ks[0][r][c]) = cvt4(pK[ii]);
    }
    __syncthreads();

    for (int t = 0; t < NKT; ++t) {
        const int cur = t & 1;
        if (t + 1 < NKT) {   // prefetch next tile; latency hides under compute
            const float* ktg = kg + (size_t)(t + 1) * KT * D;
            #pragma unroll
            for (int ii = 0; ii < 4; ++ii) {
                int idx = tid + ii * 256;
                int r = idx >> 4, c = (idx & 15) * 4;
                pK[ii] = *reinterpret_cast<const f32x4*>(ktg + r * D + c);
            }
        }
        #pragma unroll
        for (int cf = 0; cf < 4; ++cf) {
            bf16x8 aK0 = *(const bf16x8*)&Ks[cur][cf * 16 + r16][g * 8];
            bf16x8 aK1 = *(const bf16x8*)&Ks[cur][cf * 16 + r16][32 + g * 8];
            f32x4 acc = {0.f, 0.f, 0.f, 0.f};
            acc = __builtin_amdgcn_mfma_f32_16x16x32_bf16(aK0, bQ0, acc, 0, 0, 0);
            acc = __builtin_amdgcn_mfma_f32_16x16x32_bf16(aK1, bQ1, acc, 0, 0, 0);
            #pragma unroll
            for (int e = 0; e < 4; ++e)
                rs += __expf(acc[e] * (1.0f / 64.0f));
        }
        if (t + 1 < NKT) {
            const int nxt = (t + 1) & 1;
            #pragma unroll
            for (int ii = 0; ii < 4; ++ii) {
                int idx = tid + ii * 256;
                int r = idx >> 4, c = (idx & 15) * 4;
                *reinterpret_cast<bf16x4*>(&Ks[nxt][r][c]) = cvt4(pK[ii]);
            }
            __syncthreads();
        }
    }
    rs += __shfl_xor(rs, 16, 64);
    rs += __shfl_xor(rs, 32, 64);
    const float inv = 1.0f / rs;

    // ====== phase 2: recompute scores, attn via LDS (full-line stores), PV ======
    f32x4 oacc[4];
    #pragma unroll
    for (int n = 0; n < 4; ++n) oacc[n] = {0.f, 0.f, 0.f, 0.f};

    f32x4 pV[4];
    const int vk0 = (tid & 15) * 4;   // V: 4 rows x float4 -> transposed b64 writes
    const int vc  = (tid >> 4) * 4;

    #pragma unroll
    for (int ii = 0; ii < 4; ++ii) {
        int idx = tid + ii * 256;
        int r = idx >> 4, c = (idx & 15) * 4;
        pK[ii] = *reinterpret_cast<const f32x4*>(kg + r * D + c);
        pV[ii] = *reinterpret_cast<const f32x4*>(vg + (vk0 + ii) * D + vc);
    }
    #pragma unroll
    for (int ii = 0; ii < 4; ++ii) {
        int idx = tid + ii * 256;
        int r = idx >> 4, c = (idx & 15) * 4;
        *reinterpret_cast<bf16x4*>(&Ks[0][r][c]) = cvt4(pK[ii]);
    }
    #pragma unroll
    for (int j = 0; j < 4; ++j) {
        f32x4 col = { pV[0][j], pV[1][j], pV[2][j], pV[3][j] };
        *reinterpret_cast<bf16x4*>(&Vt[0][vc + j][vk0]) = cvt4(col);
    }
    __syncthreads();

    for (int t = 0; t < NKT; ++t) {
        const int cur = t & 1;
        if (t + 1 < NKT) {
            const float* ktg = kg + (size_t)(t + 1) * KT * D;
            const float* vtg = vg + (size_t)(t + 1) * KT * D;
            #pragma unroll
            for (int ii = 0; ii < 4; ++ii) {
                int idx = tid + ii * 256;
                int r = idx >> 4, c = (idx & 15) * 4;
                pK[ii] = *reinterpret_cast<const f32x4*>(ktg + r * D + c);
                pV[ii] = *reinterpret_cast<const f32x4*>(vtg + (vk0 + ii) * D + vc);
            }
        }
        // QK^T (swapped); P (normalized, bf16) -> LDS rows of this wave
        #pragma unroll
        for (int cf = 0; cf < 4; ++cf) {
            bf16x8 aK0 = *(const bf16x8*)&Ks[cur][cf * 16 + r16][g * 8];
            bf16x8 aK1 = *(const bf16x8*)&Ks[cur][cf * 16 + r16][32 + g * 8];
            f32x4 acc = {0.f, 0.f, 0.f, 0.f};
            acc = __builtin_amdgcn_mfma_f32_16x16x32_bf16(aK0, bQ0, acc, 0, 0, 0);
            acc = __builtin_amdgcn_mfma_f32_16x16x32_bf16(aK1, bQ1, acc, 0, 0, 0);
            f32x4 pst;
            #pragma unroll
            for (int e = 0; e < 4; ++e)
                pst[e] = __expf(acc[e] * (1.0f / 64.0f)) * inv;
            *reinterpret_cast<bf16x4*>(&QPs[wid * 16 + r16][cf * 16 + g * 4]) = cvt4(pst);
        }
        // PV: A = P (own-wave rows just written; same-wave DS ordering)
        bf16x8 aP0 = *(const bf16x8*)&QPs[wid * 16 + r16][g * 8];
        bf16x8 aP1 = *(const bf16x8*)&QPs[wid * 16 + r16][32 + g * 8];
        #pragma unroll
        for (int n = 0; n < 4; ++n) {
            bf16x8 bv0 = *(const bf16x8*)&Vt[cur][n * 16 + r16][g * 8];
            bf16x8 bv1 = *(const bf16x8*)&Vt[cur][n * 16 + r16][32 + g * 8];
            oacc[n] = __builtin_amdgcn_mfma_f32_16x16x32_bf16(aP0, bv0, oacc[n], 0, 0, 0);
            oacc[n] = __builtin_amdgcn_mfma_f32_16x16x32_bf16(aP1, bv1, oacc[n], 0, 0, 0);
        }
        // attn store from QPs (bf16->f32): 8 rows x (8 lanes x 16B) per instruction
        // = full 128B lines; abs error <= p * 2^-8 ~ 4e-5 (p <= ~0.01 here)
        #pragma unroll
        for (int h = 0; h < 2; ++h) {
            const int row = wid * 16 + h * 8 + sr;
            #pragma unroll
            for (int half = 0; half < 2; ++half) {
                bf16x4 pb = *reinterpret_cast<const bf16x4*>(&QPs[row][half * 32 + sc]);
                f32x4 pf = __builtin_convertvector(pb, f32x4);
                __builtin_nontemporal_store(pf, reinterpret_cast<f32x4*>(
                    attng + (size_t)row * S + t * KT + half * 32 + sc));
            }
        }
        if (t + 1 < NKT) {
            const int nxt = (t + 1) & 1;
            #pragma unroll
            for (int ii = 0; ii < 4; ++ii) {
                int idx = tid + ii * 256;
                int r = idx >> 4, c = (idx & 15) * 4;
                *reinterpret_cast<bf16x4*>(&Ks[nxt][r][c]) = cvt4(pK[ii]);
            }
            #pragma unroll
            for (int j = 0; j < 4; ++j) {
                f32x4 col = { pV[0][j], pV[1][j], pV[2][j], pV[3][j] };
                *reinterpret_cast<bf16x4*>(&Vt[nxt][vc + j][vk0]) = cvt4(col);
            }
            __syncthreads();
        }
    }

    // ---- epilogue: out tile via LDS bounce (Ks is dead) -> full-line stores ----
    __syncthreads();   // all waves done with Ks
    float* KsF = reinterpret_cast<float*>(&Ks[0][0][0]);   // 64 x 72 f32 (18.4KB fits)
    #pragma unroll
    for (int n = 0; n < 4; ++n) {
        #pragma unroll
        for (int e = 0; e < 4; ++e) {
            KsF[(wid * 16 + g * 4 + e) * 72 + n * 16 + r16] = oacc[n][e];
        }
    }
    __syncthreads();
    #pragma unroll
    for (int h = 0; h < 2; ++h) {
        const int row = wid * 16 + h * 8 + sr;
        #pragma unroll
        for (int half = 0; half < 2; ++half) {
            f32x4 o = *reinterpret_cast<const f32x4*>(&KsF[row * 72 + half * 32 + sc]);
            __builtin_nontemporal_store(o, reinterpret_cast<f32x4*>(
                outg + (size_t)row * D + half * 32 + sc));
        }
    }
}

} // namespace

extern "C" void kernel_launch(void* const* d_in, const int* in_sizes, int n_in,
                              void* d_out, int out_size, void* d_ws, size_t ws_size,
                              hipStream_t stream) {
    const float* q = (const float*)d_in[0];
    const float* k = (const float*)d_in[1];
    const float* v = (const float*)d_in[2];
    float* out  = (float*)d_out;
    float* attn = out + (size_t)BH * S * D;   // outputs concatenated: (out, attn)

    dim3 grid(S / QT, BH);
    sdpa_kernel<<<grid, 256, 0, stream>>>(q, k, v, out, attn);
}